// Round 7
// baseline (766.064 us; speedup 1.0000x reference)
//
#include <hip/hip_runtime.h>

#define D_H 32
#define NREP 32
#define BK   64    // nodes per bucket
#define BKB  6     // log2(BK)
#define SUB  32    // sub-cursors per bucket (kills atomic contention; R6-proven)

// ---------------- binning: (dst-bucket, e&31) counting sort ----------------

__global__ void k_bhist(const int* __restrict__ dst, int* __restrict__ cnt, int E) {
    int e = blockIdx.x * blockDim.x + threadIdx.x;
    if (e < E) atomicAdd(&cnt[(dst[e] >> BKB) * SUB + (e & (SUB - 1))], 1);
}

// Level-1 scan: thread c sums cnt[c*128 .. +127] (c < NCH), then block-wide
// exclusive scan over 1024 chunk sums -> chunkOff.
__global__ void k_scanA2(const int* __restrict__ cnt, int* __restrict__ chunkOff,
                         int NCH) {
    __shared__ int sh[1024];
    int c = threadIdx.x;
    int s = 0;
    if (c < NCH) {
        const int4* p = (const int4*)(cnt + c * 128);
#pragma unroll
        for (int q = 0; q < 32; ++q) { int4 v = p[q]; s += v.x + v.y + v.z + v.w; }
    }
    sh[c] = s;
    __syncthreads();
    for (int off = 1; off < 1024; off <<= 1) {
        int v = (c >= off) ? sh[c - off] : 0;
        __syncthreads();
        sh[c] += v;
        __syncthreads();
    }
    chunkOff[c] = sh[c] - s;   // exclusive
}

// Level-2 scan: block c scans its 128-entry chunk; writes soffs[i] (i<=M) and
// initializes cursor[i] (i<M).
__global__ void k_scanB2(const int* __restrict__ cnt, const int* __restrict__ chunkOff,
                         int* __restrict__ soffs, int* __restrict__ cursor, int M) {
    __shared__ int sh[128];
    int c = blockIdx.x, t = threadIdx.x;
    int i = c * 128 + t;
    int val = (i < M) ? cnt[i] : 0;
    sh[t] = val;
    __syncthreads();
    for (int off = 1; off < 128; off <<= 1) {
        int v = (t >= off) ? sh[t - off] : 0;
        __syncthreads();
        sh[t] += v;
        __syncthreads();
    }
    int excl = chunkOff[c] + sh[t] - val;
    if (i <= M) soffs[i] = excl;
    if (i < M) cursor[i] = excl;
}

// Scatter (src,dst) pairs into bucket-sorted order.
__global__ void k_fill2(const int* __restrict__ src, const int* __restrict__ dst,
                        int* __restrict__ cursor, int2* __restrict__ epk, int E) {
    int e = blockIdx.x * blockDim.x + threadIdx.x;
    if (e < E) {
        int d = dst[e];
        int pos = atomicAdd(&cursor[(d >> BKB) * SUB + (e & (SUB - 1))], 1);
        epk[pos] = make_int2(src[e], d);
    }
}

// ---------------- node projections ----------------

// Fused input-net + projection (iter 0). One thread per node; weights at
// wave-uniform indices -> scalar loads. A = (f@W1^T + b_c) - f@W2^T, B = f@W2^T.
__global__ void k_ab0(const float* __restrict__ x, const float* __restrict__ W_in,
                      const float* __restrict__ b_in, const float* __restrict__ W_c,
                      const float* __restrict__ b_c, float* __restrict__ A,
                      float* __restrict__ B, int N) {
    int n = blockIdx.x * blockDim.x + threadIdx.x;
    if (n >= N) return;
    float f[48];
    const float4* xr = (const float4*)(x + (size_t)n * 16);
#pragma unroll
    for (int q = 0; q < 4; ++q) {
        float4 v = xr[q];
        f[32 + 4 * q] = v.x; f[33 + 4 * q] = v.y;
        f[34 + 4 * q] = v.z; f[35 + 4 * q] = v.w;
    }
#pragma unroll
    for (int j = 0; j < 32; ++j) {
        const float* w = W_in + j * 16;
        float acc = b_in[j];
#pragma unroll
        for (int i = 0; i < 16; ++i) acc += f[32 + i] * w[i];
        f[j] = tanhf(acc);
    }
#pragma unroll 4
    for (int j = 0; j < 32; ++j) {
        const float* w = W_c + j * 96;
        float p = b_c[j];
        float bb = 0.f;
#pragma unroll
        for (int i = 0; i < 48; ++i) {
            p  += f[i] * w[i];
            bb += f[i] * w[48 + i];
        }
        A[(size_t)n * D_H + j] = p - bb;
        B[(size_t)n * D_H + j] = bb;
    }
}

// Projection for iter 1: feats = [H, x].
__global__ void k_ab1(const float* __restrict__ H, const float* __restrict__ x,
                      const float* __restrict__ W_c, const float* __restrict__ b_c,
                      float* __restrict__ A, float* __restrict__ B, int N) {
    int n = blockIdx.x * blockDim.x + threadIdx.x;
    if (n >= N) return;
    float f[48];
    const float4* hr = (const float4*)(H + (size_t)n * D_H);
#pragma unroll
    for (int q = 0; q < 8; ++q) {
        float4 v = hr[q];
        f[4 * q]     = v.x; f[4 * q + 1] = v.y;
        f[4 * q + 2] = v.z; f[4 * q + 3] = v.w;
    }
    const float4* xr = (const float4*)(x + (size_t)n * 16);
#pragma unroll
    for (int q = 0; q < 4; ++q) {
        float4 v = xr[q];
        f[32 + 4 * q] = v.x; f[33 + 4 * q] = v.y;
        f[34 + 4 * q] = v.z; f[35 + 4 * q] = v.w;
    }
#pragma unroll 4
    for (int j = 0; j < 32; ++j) {
        const float* w = W_c + j * 96;
        float p = b_c[j];
        float bb = 0.f;
#pragma unroll
        for (int i = 0; i < 48; ++i) {
            p  += f[i] * w[i];
            bb += f[i] * w[48 + i];
        }
        A[(size_t)n * D_H + j] = p - bb;
        B[(size_t)n * D_H + j] = bb;
    }
}

// ---------------- edge pass (sorted, fire-and-forget, XCD-swizzled) ----------------

__device__ __forceinline__ float sigm(float v) {
    return 1.f / (1.f + __expf(-v));
}

// One 32-lane slot per edge; edges are bucket-sorted by dst, and the block
// swizzle keeps consecutive edge chunks on one XCD so A lines and H atomic
// targets stay XCD-L2-local. Max TLP (R2's proven regime), halved A traffic,
// write-merged H atomics.
__global__ __launch_bounds__(256) void
k_sedge(const int2* __restrict__ epk, const float* __restrict__ A,
        const float* __restrict__ B, float* __restrict__ H, int E, int G8) {
    int b = blockIdx.x;
    int c = (b & 7) * G8 + (b >> 3);   // chunk id; consecutive c on same XCD
    int e = c * 8 + (threadIdx.x >> 5);
    int k = threadIdx.x & 31;
    if (e >= E) return;
    int2 sd = epk[e];                  // slot-uniform 8B load (broadcast)
    float v = A[(size_t)sd.y * D_H + k] + B[(size_t)sd.x * D_H + k];
    unsafeAtomicAdd(&H[(size_t)sd.y * D_H + k], sigm(v));
}

// Column sums of H into Srep (replicated to avoid line contention).
__global__ void k_reduceS(const float* __restrict__ H, float* __restrict__ Srep, int N) {
    int k = threadIdx.x & 31;
    int row = threadIdx.x >> 5;               // 0..7
    int node = blockIdx.x * 8 + row;
    int stride = gridDim.x * 8;
    float acc = 0.f;
    for (int n = node; n < N; n += stride) acc += H[(size_t)n * D_H + k];
    __shared__ float red[8][32];
    red[row][k] = acc;
    __syncthreads();
    if (threadIdx.x < 32) {
        float s = 0.f;
#pragma unroll
        for (int r = 0; r < 8; ++r) s += red[r][threadIdx.x];
        unsafeAtomicAdd(&Srep[(blockIdx.x & (NREP - 1)) * D_H + threadIdx.x], s);
    }
}

// Fallback (R2-proven) scatter path, iter 0.
__global__ void k_edge1(const int* __restrict__ src, const int* __restrict__ dst,
                        const float* __restrict__ A, const float* __restrict__ B,
                        float* __restrict__ Hacc, int E) {
    int t = blockIdx.x * blockDim.x + threadIdx.x;
    int e = t >> 5;
    int k = t & 31;
    if (e >= E) return;
    int d = dst[e];
    int s = src[e];
    float v = A[(size_t)d * D_H + k] + B[(size_t)s * D_H + k];
    unsafeAtomicAdd(&Hacc[(size_t)d * D_H + k], sigm(v));
}

// Fallback scatter path, iter 1 fused with global mean (edge-strided).
__global__ void k_edge2(const int* __restrict__ src, const int* __restrict__ dst,
                        const float* __restrict__ A, const float* __restrict__ B,
                        float* __restrict__ Srep, int E) {
    int k = threadIdx.x & 31;
    int slot = threadIdx.x >> 5;
    int e0 = blockIdx.x * 8 + slot;
    int stride = gridDim.x * 8;
    float acc = 0.f;
    for (int e = e0; e < E; e += stride) {
        int d = dst[e];
        int s = src[e];
        acc += sigm(A[(size_t)d * D_H + k] + B[(size_t)s * D_H + k]);
    }
    __shared__ float red[8][32];
    red[slot][k] = acc;
    __syncthreads();
    if (threadIdx.x < 32) {
        float s = 0.f;
#pragma unroll
        for (int r = 0; r < 8; ++r) s += red[r][threadIdx.x];
        unsafeAtomicAdd(&Srep[(blockIdx.x & (NREP - 1)) * D_H + threadIdx.x], s);
    }
}

// out = sigmoid(W_out . (S/N) + b_out), S = sum over replicas.
__global__ void k_final(const float* __restrict__ Srep, const float* __restrict__ W_out,
                        const float* __restrict__ b_out, float* __restrict__ out,
                        float invN) {
    int j = threadIdx.x;  // 0..63
    float v = 0.f;
    if (j < 32) {
        float s = 0.f;
#pragma unroll
        for (int r = 0; r < NREP; ++r) s += Srep[r * D_H + j];
        v = s * invN * W_out[j];
    }
#pragma unroll
    for (int off = 32; off > 0; off >>= 1) v += __shfl_down(v, off);
    if (j == 0) out[0] = 1.f / (1.f + __expf(-(v + b_out[0])));
}

extern "C" void kernel_launch(void* const* d_in, const int* in_sizes, int n_in,
                              void* d_out, int out_size, void* d_ws, size_t ws_size,
                              hipStream_t stream) {
    const float* x     = (const float*)d_in[0];
    const int*   ei    = (const int*)d_in[1];
    const float* W_in  = (const float*)d_in[2];
    const float* b_in  = (const float*)d_in[3];
    const float* W_c   = (const float*)d_in[4];
    const float* b_c   = (const float*)d_in[5];
    const float* W_out = (const float*)d_in[6];
    const float* b_out = (const float*)d_in[7];

    const int N = in_sizes[0] / 16;
    const int E = in_sizes[1] / 2;
    const int* src = ei;        // edge_index[0]
    const int* dst = ei + E;    // edge_index[1]

    const int NB  = (N + BK - 1) / BK;     // 1563 for N=100000
    const int M   = NB * SUB;              // sub-cursor count (50016)
    const int NCH = (M + 127) / 128;       // scan chunks (391, must be <=1024)
    const int MP  = NCH * 128;             // padded cnt size

    // edge-chunk grid for k_sedge: 8 edges per block, padded to multiple of 8
    const int NCHK  = (E + 7) / 8;
    const int G8    = (NCHK + 7) / 8;      // chunks per XCD lane
    const int GRID  = G8 * 8;

    // ---- workspace layout ----
    float* H    = (float*)d_ws;                 // N*32
    float* A    = H + (size_t)N * D_H;          // N*32
    float* B    = A + (size_t)N * D_H;          // N*32
    float* Srep = B + (size_t)N * D_H;          // NREP*32 = 1024
    int* cnt      = (int*)(Srep + NREP * D_H);  // MP (zero-padded, 16B-aligned)
    int* chunkOff = cnt + MP;                   // 1024
    int* soffs    = chunkOff + 1024;            // M+1
    int* cursor   = soffs + (M + 1);            // M (+1 pad keeps epk 8B-aligned)
    int2* epk     = (int2*)(cursor + M + 1);    // E pairs

    size_t need_base = ((size_t)3 * N * D_H + NREP * D_H) * 4;
    size_t need_bin  = need_base +
                       ((size_t)MP + 1024 + (M + 1) + (M + 1)) * 4 + (size_t)E * 8;
    bool use_bin = (ws_size >= need_bin) && (NCH <= 1024);

    float* out = (float*)d_out;

    if (use_bin) {
        // ---- binning (once; reused by both edge passes) ----
        hipMemsetAsync(cnt, 0, (size_t)MP * sizeof(int), stream);
        k_bhist<<<(E + 255) / 256, 256, 0, stream>>>(dst, cnt, E);
        k_scanA2<<<1, 1024, 0, stream>>>(cnt, chunkOff, NCH);
        k_scanB2<<<NCH, 128, 0, stream>>>(cnt, chunkOff, soffs, cursor, M);
        k_fill2<<<(E + 255) / 256, 256, 0, stream>>>(src, dst, cursor, epk, E);

        // ---- Iteration 0 ----
        k_ab0<<<(N + 255) / 256, 256, 0, stream>>>(x, W_in, b_in, W_c, b_c, A, B, N);
        hipMemsetAsync(H, 0, (size_t)N * D_H * sizeof(float), stream);
        k_sedge<<<GRID, 256, 0, stream>>>(epk, A, B, H, E, G8);

        // ---- Iteration 1 ----
        k_ab1<<<(N + 255) / 256, 256, 0, stream>>>(H, x, W_c, b_c, A, B, N);
        hipMemsetAsync(H, 0, (size_t)N * D_H * sizeof(float), stream);
        k_sedge<<<GRID, 256, 0, stream>>>(epk, A, B, H, E, G8);

        // ---- Global mean ----
        hipMemsetAsync(Srep, 0, NREP * D_H * sizeof(float), stream);
        k_reduceS<<<256, 256, 0, stream>>>(H, Srep, N);
    } else {
        // ---- Fallback: R2-proven scatter path ----
        k_ab0<<<(N + 255) / 256, 256, 0, stream>>>(x, W_in, b_in, W_c, b_c, A, B, N);
        hipMemsetAsync(H, 0, (size_t)N * D_H * sizeof(float), stream);
        k_edge1<<<(int)(((size_t)E * 32 + 255) / 256), 256, 0, stream>>>(src, dst, A, B, H, E);

        k_ab1<<<(N + 255) / 256, 256, 0, stream>>>(H, x, W_c, b_c, A, B, N);
        hipMemsetAsync(Srep, 0, NREP * D_H * sizeof(float), stream);
        k_edge2<<<2048, 256, 0, stream>>>(src, dst, A, B, Srep, E);
    }

    k_final<<<1, 64, 0, stream>>>(Srep, W_out, b_out, out, 1.f / (float)N);
}

// Round 8
// 727.236 us; speedup vs baseline: 1.0534x; 1.0534x over previous
//
#include <hip/hip_runtime.h>

#define D_H 32
#define NREP 32
#define BK   64    // nodes per bucket
#define BKB  6     // log2(BK)
#define SUB  32    // sub-cursors per bucket (kills atomic contention; R6-proven)

// ---------------- binning: (dst-bucket, e&31) counting sort ----------------

__global__ void k_bhist(const int* __restrict__ dst, int* __restrict__ cnt, int E) {
    int e = blockIdx.x * blockDim.x + threadIdx.x;
    if (e < E) atomicAdd(&cnt[(dst[e] >> BKB) * SUB + (e & (SUB - 1))], 1);
}

// Level-1 scan: thread c sums cnt[c*128 .. +127] (c < NCH), then block-wide
// exclusive scan over 1024 chunk sums -> chunkOff.
__global__ void k_scanA2(const int* __restrict__ cnt, int* __restrict__ chunkOff,
                         int NCH) {
    __shared__ int sh[1024];
    int c = threadIdx.x;
    int s = 0;
    if (c < NCH) {
        const int4* p = (const int4*)(cnt + c * 128);
#pragma unroll
        for (int q = 0; q < 32; ++q) { int4 v = p[q]; s += v.x + v.y + v.z + v.w; }
    }
    sh[c] = s;
    __syncthreads();
    for (int off = 1; off < 1024; off <<= 1) {
        int v = (c >= off) ? sh[c - off] : 0;
        __syncthreads();
        sh[c] += v;
        __syncthreads();
    }
    chunkOff[c] = sh[c] - s;   // exclusive
}

// Level-2 scan: block c scans its 128-entry chunk; writes soffs[i] (i<=M) and
// initializes cursor[i] (i<M).
__global__ void k_scanB2(const int* __restrict__ cnt, const int* __restrict__ chunkOff,
                         int* __restrict__ soffs, int* __restrict__ cursor, int M) {
    __shared__ int sh[128];
    int c = blockIdx.x, t = threadIdx.x;
    int i = c * 128 + t;
    int val = (i < M) ? cnt[i] : 0;
    sh[t] = val;
    __syncthreads();
    for (int off = 1; off < 128; off <<= 1) {
        int v = (t >= off) ? sh[t - off] : 0;
        __syncthreads();
        sh[t] += v;
        __syncthreads();
    }
    int excl = chunkOff[c] + sh[t] - val;
    if (i <= M) soffs[i] = excl;
    if (i < M) cursor[i] = excl;
}

// Append packed (src<<BKB | dst&(BK-1)). ~32 edges per sub-cursor -> low
// contention; 4B payload (src<2^26 fits).
__global__ void k_bfill(const int* __restrict__ src, const int* __restrict__ dst,
                        int* __restrict__ cursor, unsigned* __restrict__ packed, int E) {
    int e = blockIdx.x * blockDim.x + threadIdx.x;
    if (e < E) {
        int d = dst[e];
        int pos = atomicAdd(&cursor[(d >> BKB) * SUB + (e & (SUB - 1))], 1);
        packed[pos] = ((unsigned)src[e] << BKB) | (unsigned)(d & (BK - 1));
    }
}

// ---------------- node projections ----------------

// Fused input-net + projection (iter 0). One thread per node; weights at
// wave-uniform indices -> scalar loads. A = (f@W1^T + b_c) - f@W2^T, B = f@W2^T.
__global__ void k_ab0(const float* __restrict__ x, const float* __restrict__ W_in,
                      const float* __restrict__ b_in, const float* __restrict__ W_c,
                      const float* __restrict__ b_c, float* __restrict__ A,
                      float* __restrict__ B, int N) {
    int n = blockIdx.x * blockDim.x + threadIdx.x;
    if (n >= N) return;
    float f[48];
    const float4* xr = (const float4*)(x + (size_t)n * 16);
#pragma unroll
    for (int q = 0; q < 4; ++q) {
        float4 v = xr[q];
        f[32 + 4 * q] = v.x; f[33 + 4 * q] = v.y;
        f[34 + 4 * q] = v.z; f[35 + 4 * q] = v.w;
    }
#pragma unroll
    for (int j = 0; j < 32; ++j) {
        const float* w = W_in + j * 16;
        float acc = b_in[j];
#pragma unroll
        for (int i = 0; i < 16; ++i) acc += f[32 + i] * w[i];
        f[j] = tanhf(acc);
    }
#pragma unroll 4
    for (int j = 0; j < 32; ++j) {
        const float* w = W_c + j * 96;
        float p = b_c[j];
        float bb = 0.f;
#pragma unroll
        for (int i = 0; i < 48; ++i) {
            p  += f[i] * w[i];
            bb += f[i] * w[48 + i];
        }
        A[(size_t)n * D_H + j] = p - bb;
        B[(size_t)n * D_H + j] = bb;
    }
}

// Projection for iter 1: feats = [H, x].
__global__ void k_ab1(const float* __restrict__ H, const float* __restrict__ x,
                      const float* __restrict__ W_c, const float* __restrict__ b_c,
                      float* __restrict__ A, float* __restrict__ B, int N) {
    int n = blockIdx.x * blockDim.x + threadIdx.x;
    if (n >= N) return;
    float f[48];
    const float4* hr = (const float4*)(H + (size_t)n * D_H);
#pragma unroll
    for (int q = 0; q < 8; ++q) {
        float4 v = hr[q];
        f[4 * q]     = v.x; f[4 * q + 1] = v.y;
        f[4 * q + 2] = v.z; f[4 * q + 3] = v.w;
    }
    const float4* xr = (const float4*)(x + (size_t)n * 16);
#pragma unroll
    for (int q = 0; q < 4; ++q) {
        float4 v = xr[q];
        f[32 + 4 * q] = v.x; f[33 + 4 * q] = v.y;
        f[34 + 4 * q] = v.z; f[35 + 4 * q] = v.w;
    }
#pragma unroll 4
    for (int j = 0; j < 32; ++j) {
        const float* w = W_c + j * 96;
        float p = b_c[j];
        float bb = 0.f;
#pragma unroll
        for (int i = 0; i < 48; ++i) {
            p  += f[i] * w[i];
            bb += f[i] * w[48 + i];
        }
        A[(size_t)n * D_H + j] = p - bb;
        B[(size_t)n * D_H + j] = bb;
    }
}

// ---------------- edge passes (LDS-accumulating, HW fp atomics) ----------------

__device__ __forceinline__ float sigm(float v) {
    return 1.f / (1.f + __expf(-v));
}

// Iter 0: one block per bucket. A-tile in LDS, H-tile accumulated via
// ds_add_f32 (unsafeAtomicAdd -> HW LDS fp atomic; bank = lane -> conflict-
// free), coalesced H store. No global atomics. [R6 structure; CAS-loop fixed]
__global__ __launch_bounds__(256) void
k_bedge1(const int* __restrict__ soffs, const unsigned* __restrict__ packed,
         const float* __restrict__ A, const float* __restrict__ B,
         float* __restrict__ H, int N) {
    __shared__ float Aloc[BK * D_H];
    __shared__ float Hloc[BK * D_H];
    int b = blockIdx.x;
    int base = b << BKB;
    int nn = min(BK, N - base);
    int t = threadIdx.x;
    int nv = nn * 8;  // float4 count
    const float4* Ag = (const float4*)(A + (size_t)base * D_H);
    float4* Al4 = (float4*)Aloc;
    float4* Hl4 = (float4*)Hloc;
    for (int i = t; i < nv; i += 256) {
        Al4[i] = Ag[i];
        Hl4[i] = make_float4(0.f, 0.f, 0.f, 0.f);
    }
    __syncthreads();
    int p0 = soffs[b * SUB], p1 = soffs[(b + 1) * SUB];
    int k = t & 31, slot = t >> 5;
    int p = p0 + slot;
    for (; p + 24 < p1; p += 32) {   // 4 edges per slot per iter for MLP
        unsigned w0 = packed[p], w1 = packed[p + 8];
        unsigned w2 = packed[p + 16], w3 = packed[p + 24];
        float g0 = B[(size_t)(w0 >> BKB) * D_H + k];
        float g1 = B[(size_t)(w1 >> BKB) * D_H + k];
        float g2 = B[(size_t)(w2 >> BKB) * D_H + k];
        float g3 = B[(size_t)(w3 >> BKB) * D_H + k];
        unsafeAtomicAdd(&Hloc[(w0 & (BK - 1)) * D_H + k], sigm(Aloc[(w0 & (BK - 1)) * D_H + k] + g0));
        unsafeAtomicAdd(&Hloc[(w1 & (BK - 1)) * D_H + k], sigm(Aloc[(w1 & (BK - 1)) * D_H + k] + g1));
        unsafeAtomicAdd(&Hloc[(w2 & (BK - 1)) * D_H + k], sigm(Aloc[(w2 & (BK - 1)) * D_H + k] + g2));
        unsafeAtomicAdd(&Hloc[(w3 & (BK - 1)) * D_H + k], sigm(Aloc[(w3 & (BK - 1)) * D_H + k] + g3));
    }
    for (; p < p1; p += 8) {
        unsigned w = packed[p];
        int dl = w & (BK - 1);
        float v = Aloc[dl * D_H + k] + B[(size_t)(w >> BKB) * D_H + k];
        unsafeAtomicAdd(&Hloc[dl * D_H + k], sigm(v));
    }
    __syncthreads();
    float4* Hg = (float4*)(H + (size_t)base * D_H);
    for (int i = t; i < nv; i += 256) Hg[i] = Hl4[i];
}

// Iter 1 fused with global mean: register accumulation, no H materialization.
__global__ __launch_bounds__(256) void
k_bedge2(const int* __restrict__ soffs, const unsigned* __restrict__ packed,
         const float* __restrict__ A, const float* __restrict__ B,
         float* __restrict__ Srep, int N) {
    __shared__ float Aloc[BK * D_H];
    __shared__ float red[8][32];
    int b = blockIdx.x;
    int base = b << BKB;
    int nn = min(BK, N - base);
    int t = threadIdx.x;
    const float4* Ag = (const float4*)(A + (size_t)base * D_H);
    float4* Al4 = (float4*)Aloc;
    for (int i = t; i < nn * 8; i += 256) Al4[i] = Ag[i];
    __syncthreads();
    int p0 = soffs[b * SUB], p1 = soffs[(b + 1) * SUB];
    int k = t & 31, slot = t >> 5;
    float acc = 0.f;
    int p = p0 + slot;
    for (; p + 24 < p1; p += 32) {
        unsigned w0 = packed[p], w1 = packed[p + 8];
        unsigned w2 = packed[p + 16], w3 = packed[p + 24];
        float g0 = B[(size_t)(w0 >> BKB) * D_H + k];
        float g1 = B[(size_t)(w1 >> BKB) * D_H + k];
        float g2 = B[(size_t)(w2 >> BKB) * D_H + k];
        float g3 = B[(size_t)(w3 >> BKB) * D_H + k];
        acc += sigm(Aloc[(w0 & (BK - 1)) * D_H + k] + g0);
        acc += sigm(Aloc[(w1 & (BK - 1)) * D_H + k] + g1);
        acc += sigm(Aloc[(w2 & (BK - 1)) * D_H + k] + g2);
        acc += sigm(Aloc[(w3 & (BK - 1)) * D_H + k] + g3);
    }
    for (; p < p1; p += 8) {
        unsigned w = packed[p];
        acc += sigm(Aloc[(w & (BK - 1)) * D_H + k] + B[(size_t)(w >> BKB) * D_H + k]);
    }
    __syncthreads();
    red[slot][k] = acc;
    __syncthreads();
    if (t < 32) {
        float s = 0.f;
#pragma unroll
        for (int r = 0; r < 8; ++r) s += red[r][t];
        unsafeAtomicAdd(&Srep[(b & (NREP - 1)) * D_H + t], s);
    }
}

// Fallback (R2-proven) scatter path, iter 0.
__global__ void k_edge1(const int* __restrict__ src, const int* __restrict__ dst,
                        const float* __restrict__ A, const float* __restrict__ B,
                        float* __restrict__ Hacc, int E) {
    int t = blockIdx.x * blockDim.x + threadIdx.x;
    int e = t >> 5;
    int k = t & 31;
    if (e >= E) return;
    int d = dst[e];
    int s = src[e];
    float v = A[(size_t)d * D_H + k] + B[(size_t)s * D_H + k];
    unsafeAtomicAdd(&Hacc[(size_t)d * D_H + k], sigm(v));
}

// Fallback scatter path, iter 1 fused with global mean (edge-strided).
__global__ void k_edge2(const int* __restrict__ src, const int* __restrict__ dst,
                        const float* __restrict__ A, const float* __restrict__ B,
                        float* __restrict__ Srep, int E) {
    int k = threadIdx.x & 31;
    int slot = threadIdx.x >> 5;
    int e0 = blockIdx.x * 8 + slot;
    int stride = gridDim.x * 8;
    float acc = 0.f;
    for (int e = e0; e < E; e += stride) {
        int d = dst[e];
        int s = src[e];
        acc += sigm(A[(size_t)d * D_H + k] + B[(size_t)s * D_H + k]);
    }
    __shared__ float red[8][32];
    red[slot][k] = acc;
    __syncthreads();
    if (threadIdx.x < 32) {
        float s = 0.f;
#pragma unroll
        for (int r = 0; r < 8; ++r) s += red[r][threadIdx.x];
        unsafeAtomicAdd(&Srep[(blockIdx.x & (NREP - 1)) * D_H + threadIdx.x], s);
    }
}

// out = sigmoid(W_out . (S/N) + b_out), S = sum over replicas.
__global__ void k_final(const float* __restrict__ Srep, const float* __restrict__ W_out,
                        const float* __restrict__ b_out, float* __restrict__ out,
                        float invN) {
    int j = threadIdx.x;  // 0..63
    float v = 0.f;
    if (j < 32) {
        float s = 0.f;
#pragma unroll
        for (int r = 0; r < NREP; ++r) s += Srep[r * D_H + j];
        v = s * invN * W_out[j];
    }
#pragma unroll
    for (int off = 32; off > 0; off >>= 1) v += __shfl_down(v, off);
    if (j == 0) out[0] = 1.f / (1.f + __expf(-(v + b_out[0])));
}

extern "C" void kernel_launch(void* const* d_in, const int* in_sizes, int n_in,
                              void* d_out, int out_size, void* d_ws, size_t ws_size,
                              hipStream_t stream) {
    const float* x     = (const float*)d_in[0];
    const int*   ei    = (const int*)d_in[1];
    const float* W_in  = (const float*)d_in[2];
    const float* b_in  = (const float*)d_in[3];
    const float* W_c   = (const float*)d_in[4];
    const float* b_c   = (const float*)d_in[5];
    const float* W_out = (const float*)d_in[6];
    const float* b_out = (const float*)d_in[7];

    const int N = in_sizes[0] / 16;
    const int E = in_sizes[1] / 2;
    const int* src = ei;        // edge_index[0]
    const int* dst = ei + E;    // edge_index[1]

    const int NB  = (N + BK - 1) / BK;     // 1563 for N=100000
    const int M   = NB * SUB;              // sub-cursor count (50016)
    const int NCH = (M + 127) / 128;       // scan chunks (391, must be <=1024)
    const int MP  = NCH * 128;             // padded cnt size

    // ---- workspace layout ----
    float* H    = (float*)d_ws;                 // N*32
    float* A    = H + (size_t)N * D_H;          // N*32
    float* B    = A + (size_t)N * D_H;          // N*32
    float* Srep = B + (size_t)N * D_H;          // NREP*32 = 1024
    int* cnt      = (int*)(Srep + NREP * D_H);  // MP (zero-padded, 16B-aligned)
    int* chunkOff = cnt + MP;                   // 1024
    int* soffs    = chunkOff + 1024;            // M+1
    int* cursor   = soffs + (M + 1);            // M
    unsigned* packed = (unsigned*)(cursor + M); // E

    size_t need_base = ((size_t)3 * N * D_H + NREP * D_H) * 4;
    size_t need_bin  = need_base + ((size_t)MP + 1024 + (M + 1) + M + E) * 4;
    bool use_bin = (ws_size >= need_bin) && (NCH <= 1024);

    float* out = (float*)d_out;

    if (use_bin) {
        // ---- binning (once; reused by both edge passes) ----
        hipMemsetAsync(cnt, 0, (size_t)MP * sizeof(int), stream);
        k_bhist<<<(E + 255) / 256, 256, 0, stream>>>(dst, cnt, E);
        k_scanA2<<<1, 1024, 0, stream>>>(cnt, chunkOff, NCH);
        k_scanB2<<<NCH, 128, 0, stream>>>(cnt, chunkOff, soffs, cursor, M);
        k_bfill<<<(E + 255) / 256, 256, 0, stream>>>(src, dst, cursor, packed, E);

        // ---- Iteration 0 ----
        k_ab0<<<(N + 255) / 256, 256, 0, stream>>>(x, W_in, b_in, W_c, b_c, A, B, N);
        k_bedge1<<<NB, 256, 0, stream>>>(soffs, packed, A, B, H, N);

        // ---- Iteration 1 + global mean ----
        k_ab1<<<(N + 255) / 256, 256, 0, stream>>>(H, x, W_c, b_c, A, B, N);
        hipMemsetAsync(Srep, 0, NREP * D_H * sizeof(float), stream);
        k_bedge2<<<NB, 256, 0, stream>>>(soffs, packed, A, B, Srep, N);
    } else {
        // ---- Fallback: R2-proven scatter path ----
        k_ab0<<<(N + 255) / 256, 256, 0, stream>>>(x, W_in, b_in, W_c, b_c, A, B, N);
        hipMemsetAsync(H, 0, (size_t)N * D_H * sizeof(float), stream);
        k_edge1<<<(int)(((size_t)E * 32 + 255) / 256), 256, 0, stream>>>(src, dst, A, B, H, E);

        k_ab1<<<(N + 255) / 256, 256, 0, stream>>>(H, x, W_c, b_c, A, B, N);
        hipMemsetAsync(Srep, 0, NREP * D_H * sizeof(float), stream);
        k_edge2<<<2048, 256, 0, stream>>>(src, dst, A, B, Srep, E);
    }

    k_final<<<1, 64, 0, stream>>>(Srep, W_out, b_out, out, 1.f / (float)N);
}